// Round 3
// baseline (5015.708 us; speedup 1.0000x reference)
//
#include <hip/hip_runtime.h>
#include <math.h>

// Problem constants
#define TSTEPS 19   // T-1 decode steps
#define NB 64       // batch
#define NS 64       // src len
#define NT 20       // tgt len
#define NH 512      // hidden
#define NE 256      // emb dim
#define NV 32000    // vocab
#define NBLK 256    // recurrence grid size (must all be co-resident)

// ---------------------------------------------------------------------------
// Fast grid barrier: sense-reversing via (count, generation) pair in d_ws.
// All NBLK blocks must be co-resident (cooperative launch guarantees this).
// ACQ_REL on the arrival add + ACQ on the spin load gives transitive
// happens-before: every block's pre-barrier stores are visible after exit.
// cg::grid.sync() measured ~65us/sync (r2: 3008us/38 syncs with idle pipes);
// this is ~3-5us.
// ---------------------------------------------------------------------------
__device__ __forceinline__ void grid_barrier(unsigned* cnt, unsigned* gen) {
  __syncthreads();
  if (threadIdx.x == 0) {
    unsigned g = __hip_atomic_load(gen, __ATOMIC_RELAXED, __HIP_MEMORY_SCOPE_AGENT);
    unsigned old = __hip_atomic_fetch_add(cnt, 1u, __ATOMIC_ACQ_REL, __HIP_MEMORY_SCOPE_AGENT);
    if (old == NBLK - 1) {
      // reset count BEFORE releasing the new generation (sense reversal)
      __hip_atomic_store(cnt, 0u, __ATOMIC_RELAXED, __HIP_MEMORY_SCOPE_AGENT);
      __hip_atomic_store(gen, g + 1u, __ATOMIC_RELEASE, __HIP_MEMORY_SCOPE_AGENT);
    } else {
      while (__hip_atomic_load(gen, __ATOMIC_ACQUIRE, __HIP_MEMORY_SCOPE_AGENT) == g)
        __builtin_amdgcn_s_sleep(1);
    }
  }
  __syncthreads();
}

// ---------------------------------------------------------------------------
// Generic fp32 linear: C[M,N] = A[M,K] @ W[N,K]^T (+bias). BM=64, BN=128,
// BK=16; 256 threads; 4x8 per thread. (used for enc_proj only)
// ---------------------------------------------------------------------------
__global__ __launch_bounds__(256) void linear_kernel(
    const float* __restrict__ A, int lda,
    const float* __restrict__ W, int ldw,
    const float* __restrict__ bias,
    float* __restrict__ C, int ldc,
    int K, int act)
{
  __shared__ float As[16][68];
  __shared__ float Ws[16][132];
  const int tid = threadIdx.x;
  const int m0 = blockIdx.y * 64;
  const int n0 = blockIdx.x * 128;
  const int lr = tid >> 2;
  const int lc = (tid & 3) << 2;
  const int tm = tid & 15;
  const int tn = tid >> 4;

  float acc[4][8];
#pragma unroll
  for (int i = 0; i < 4; ++i)
#pragma unroll
    for (int j = 0; j < 8; ++j) acc[i][j] = 0.f;

  const float* Ar  = A + (size_t)(m0 + lr) * lda + lc;
  const float* Wr0 = W + (size_t)(n0 + lr) * ldw + lc;
  const float* Wr1 = W + (size_t)(n0 + 64 + lr) * ldw + lc;

  for (int kk = 0; kk < K; kk += 16) {
    float4 av = *(const float4*)(Ar + kk);
    float4 w0 = *(const float4*)(Wr0 + kk);
    float4 w1 = *(const float4*)(Wr1 + kk);
    As[lc+0][lr] = av.x; As[lc+1][lr] = av.y; As[lc+2][lr] = av.z; As[lc+3][lr] = av.w;
    Ws[lc+0][lr] = w0.x; Ws[lc+1][lr] = w0.y; Ws[lc+2][lr] = w0.z; Ws[lc+3][lr] = w0.w;
    Ws[lc+0][64+lr] = w1.x; Ws[lc+1][64+lr] = w1.y; Ws[lc+2][64+lr] = w1.z; Ws[lc+3][64+lr] = w1.w;
    __syncthreads();
#pragma unroll
    for (int k = 0; k < 16; ++k) {
      float4 a4 = *(const float4*)&As[k][tm * 4];
      float4 b4 = *(const float4*)&Ws[k][tn * 8];
      float4 b5 = *(const float4*)&Ws[k][tn * 8 + 4];
      float a[4] = {a4.x, a4.y, a4.z, a4.w};
      float b[8] = {b4.x, b4.y, b4.z, b4.w, b5.x, b5.y, b5.z, b5.w};
#pragma unroll
      for (int i = 0; i < 4; ++i)
#pragma unroll
        for (int j = 0; j < 8; ++j)
          acc[i][j] = fmaf(a[i], b[j], acc[i][j]);
    }
    __syncthreads();
  }

#pragma unroll
  for (int i = 0; i < 4; ++i) {
    int m = m0 + tm * 4 + i;
    float* crow = C + (size_t)m * ldc + n0 + tn * 8;
    float vv[8];
#pragma unroll
    for (int j = 0; j < 8; ++j) {
      float v = acc[i][j];
      if (bias) v += bias[n0 + tn * 8 + j];
      if (act == 1) v = tanhf(v);
      vv[j] = v;
    }
    *(float4*)(crow)     = make_float4(vv[0], vv[1], vv[2], vv[3]);
    *(float4*)(crow + 4) = make_float4(vv[4], vv[5], vv[6], vv[7]);
  }
}

// ---------------------------------------------------------------------------
// gi_emb[t*64+b][:] = emb[tgt[b][t]] @ W_ih[:, :256]^T + b_ih   (1216 x 1536)
// ---------------------------------------------------------------------------
__global__ __launch_bounds__(256) void emb_linear_kernel(
    const float* __restrict__ emb, const int* __restrict__ tgt,
    const float* __restrict__ W_ih, const float* __restrict__ b_ih,
    float* __restrict__ C)
{
  __shared__ float As[16][68];
  __shared__ float Ws[16][132];
  const int tid = threadIdx.x;
  const int m0 = blockIdx.y * 64;
  const int n0 = blockIdx.x * 128;
  const int lr = tid >> 2;
  const int lc = (tid & 3) << 2;
  const int tm = tid & 15;
  const int tn = tid >> 4;

  float acc[4][8];
#pragma unroll
  for (int i = 0; i < 4; ++i)
#pragma unroll
    for (int j = 0; j < 8; ++j) acc[i][j] = 0.f;

  const int row = m0 + lr;                 // row = t*64 + b
  const int tok = tgt[(row & 63) * NT + (row >> 6)];
  const float* Ar  = emb + (size_t)tok * NE + lc;
  const float* Wr0 = W_ih + (size_t)(n0 + lr) * 768 + lc;
  const float* Wr1 = W_ih + (size_t)(n0 + 64 + lr) * 768 + lc;

  for (int kk = 0; kk < NE; kk += 16) {
    float4 av = *(const float4*)(Ar + kk);
    float4 w0 = *(const float4*)(Wr0 + kk);
    float4 w1 = *(const float4*)(Wr1 + kk);
    As[lc+0][lr] = av.x; As[lc+1][lr] = av.y; As[lc+2][lr] = av.z; As[lc+3][lr] = av.w;
    Ws[lc+0][lr] = w0.x; Ws[lc+1][lr] = w0.y; Ws[lc+2][lr] = w0.z; Ws[lc+3][lr] = w0.w;
    Ws[lc+0][64+lr] = w1.x; Ws[lc+1][64+lr] = w1.y; Ws[lc+2][64+lr] = w1.z; Ws[lc+3][64+lr] = w1.w;
    __syncthreads();
#pragma unroll
    for (int k = 0; k < 16; ++k) {
      float4 a4 = *(const float4*)&As[k][tm * 4];
      float4 b4 = *(const float4*)&Ws[k][tn * 8];
      float4 b5 = *(const float4*)&Ws[k][tn * 8 + 4];
      float a[4] = {a4.x, a4.y, a4.z, a4.w};
      float b[8] = {b4.x, b4.y, b4.z, b4.w, b5.x, b5.y, b5.z, b5.w};
#pragma unroll
      for (int i = 0; i < 4; ++i)
#pragma unroll
        for (int j = 0; j < 8; ++j)
          acc[i][j] = fmaf(a[i], b[j], acc[i][j]);
    }
    __syncthreads();
  }

#pragma unroll
  for (int i = 0; i < 4; ++i) {
    int m = m0 + tm * 4 + i;
    float* crow = C + (size_t)m * 1536 + n0 + tn * 8;
    float vv[8];
#pragma unroll
    for (int j = 0; j < 8; ++j) vv[j] = acc[i][j] + b_ih[n0 + tn * 8 + j];
    *(float4*)(crow)     = make_float4(vv[0], vv[1], vv[2], vv[3]);
    *(float4*)(crow + 4) = make_float4(vv[4], vv[5], vv[6], vv[7]);
  }
}

// ---------------------------------------------------------------------------
// Logits GEMM with XCD-ownership swizzle. C[1216,32000] = A @ W_out^T + b_out.
// ---------------------------------------------------------------------------
__global__ __launch_bounds__(256) void logits_kernel(
    const float* __restrict__ A, const float* __restrict__ W,
    const float* __restrict__ bias, float* __restrict__ C)
{
  const int bfl = blockIdx.x;
  const int xcd = bfl & 7;
  const int jj = bfl >> 3;
  const int mt = jj % 19;
  const int nt = xcd * 32 + jj / 19;
  if (nt >= 250) return;
  const int m0 = mt * 64;
  const int n0 = nt * 128;

  __shared__ float As[16][68];
  __shared__ float Ws[16][132];
  const int tid = threadIdx.x;
  const int lr = tid >> 2;
  const int lc = (tid & 3) << 2;
  const int tm = tid & 15;
  const int tn = tid >> 4;

  float acc[4][8];
#pragma unroll
  for (int i = 0; i < 4; ++i)
#pragma unroll
    for (int j = 0; j < 8; ++j) acc[i][j] = 0.f;

  const float* Ar  = A + (size_t)(m0 + lr) * NH + lc;
  const float* Wr0 = W + (size_t)(n0 + lr) * NH + lc;
  const float* Wr1 = W + (size_t)(n0 + 64 + lr) * NH + lc;

  for (int kk = 0; kk < NH; kk += 16) {
    float4 av = *(const float4*)(Ar + kk);
    float4 w0 = *(const float4*)(Wr0 + kk);
    float4 w1 = *(const float4*)(Wr1 + kk);
    As[lc+0][lr] = av.x; As[lc+1][lr] = av.y; As[lc+2][lr] = av.z; As[lc+3][lr] = av.w;
    Ws[lc+0][lr] = w0.x; Ws[lc+1][lr] = w0.y; Ws[lc+2][lr] = w0.z; Ws[lc+3][lr] = w0.w;
    Ws[lc+0][64+lr] = w1.x; Ws[lc+1][64+lr] = w1.y; Ws[lc+2][64+lr] = w1.z; Ws[lc+3][64+lr] = w1.w;
    __syncthreads();
#pragma unroll
    for (int k = 0; k < 16; ++k) {
      float4 a4 = *(const float4*)&As[k][tm * 4];
      float4 b4 = *(const float4*)&Ws[k][tn * 8];
      float4 b5 = *(const float4*)&Ws[k][tn * 8 + 4];
      float a[4] = {a4.x, a4.y, a4.z, a4.w};
      float b[8] = {b4.x, b4.y, b4.z, b4.w, b5.x, b5.y, b5.z, b5.w};
#pragma unroll
      for (int i = 0; i < 4; ++i)
#pragma unroll
        for (int j = 0; j < 8; ++j)
          acc[i][j] = fmaf(a[i], b[j], acc[i][j]);
    }
    __syncthreads();
  }

#pragma unroll
  for (int i = 0; i < 4; ++i) {
    int m = m0 + tm * 4 + i;
    float* crow = C + (size_t)m * NV + n0 + tn * 8;
    float vv[8];
#pragma unroll
    for (int j = 0; j < 8; ++j) vv[j] = acc[i][j] + bias[n0 + tn * 8 + j];
    *(float4*)(crow)     = make_float4(vv[0], vv[1], vv[2], vv[3]);
    *(float4*)(crow + 4) = make_float4(vv[4], vv[5], vv[6], vv[7]);
  }
}

// ---------------------------------------------------------------------------
// Recurrence: 19 steps, 3 custom barriers/step (57 total).
//   Phase A (blocks 0..191): giA = attn_prev @ W_ih[:,256:]^T (96 blocks)
//                            ghA = h_prev    @ W_hh^T         (96 blocks)
//   Phase B (blocks 0..63, one per b): gates -> h (LDS + global), scores vs
//     enc_proj (float4-coalesced), masked softmax, ctx -> global.
//   Phase C (blocks 0..63): concat GEMM attn[t+1] = tanh([h|ctx] @ Wc^T + bc)
//     n-sliced: block owns 8 rows of W_concat (read ONCE per step vs 64x in
//     the per-b version: 2MB vs 128MB of L2 traffic per step).
// ---------------------------------------------------------------------------
__global__ __launch_bounds__(256) void recur_kernel(
    const float* __restrict__ gi_emb, float* __restrict__ giA,
    float* __restrict__ ghA, float* __restrict__ hbuf,
    float* __restrict__ attn_all, float* __restrict__ ctx_g,
    const float* __restrict__ enc_proj, const float* __restrict__ enc_out,
    const int* __restrict__ len_src,
    const float* __restrict__ W_ih, const float* __restrict__ W_hh,
    const float* __restrict__ b_hh, const float* __restrict__ W_concat,
    const float* __restrict__ b_concat,
    unsigned* __restrict__ bar)
{
  unsigned* cnt = bar;
  unsigned* gen = bar + 32;   // separate cachelines
  const int blk = blockIdx.x;
  const int tid = threadIdx.x;

  __shared__ float As[64][68];   // A / X staging, [row][k], stride 68
  __shared__ float Ws[16][68];   // W staging
  __shared__ float hL[NH];       // h_new for this b (phase B)
  __shared__ float scs[NS];
  __shared__ float aw[NS];

  // staging indices (shared by phases A and C)
  const int am  = tid >> 2;          // row 0..63
  const int ac4 = (tid & 3) << 4;    // k-offset {0,16,32,48}
  const int wn  = tid >> 4;          // W row 0..15
  const int wc  = (tid & 15) << 2;   // W k-offset
  const int m   = tid & 63;          // compute row
  const int nq  = tid >> 6;          // compute col quad

  for (int t = 0; t < TSTEPS; ++t) {
    const float* attn_prev = attn_all + (size_t)t * NB * NH;
    const float* h_prev = hbuf + (size_t)(t & 1) * NB * NH;
    float* h_next = hbuf + (size_t)((t & 1) ^ 1) * NB * NH;

    // ---------------- Phase A: gi/gh GEMMs ----------------
    if (blk < 192) {
      const int half = blk / 96;
      const int n0 = (blk % 96) * 16;
      const float* Asrc = half ? h_prev : attn_prev;
      const float* Wsrc = half ? W_hh : (W_ih + NE);
      const int ldw = half ? NH : (NE + NH);
      float* Cdst = half ? ghA : giA;

      float acc[4] = {0.f, 0.f, 0.f, 0.f};
      for (int k0 = 0; k0 < NH; k0 += 64) {
#pragma unroll
        for (int u = 0; u < 4; ++u)
          *(float4*)&As[am][ac4 + 4 * u] =
              *(const float4*)(Asrc + (size_t)am * NH + k0 + ac4 + 4 * u);
        *(float4*)&Ws[wn][wc] =
            *(const float4*)(Wsrc + (size_t)(n0 + wn) * ldw + k0 + wc);
        __syncthreads();
#pragma unroll
        for (int kc4 = 0; kc4 < 16; ++kc4) {
          float4 a4 = *(const float4*)&As[m][kc4 * 4];
#pragma unroll
          for (int j = 0; j < 4; ++j) {
            float4 w4 = *(const float4*)&Ws[nq * 4 + j][kc4 * 4];
            acc[j] = fmaf(a4.x, w4.x, acc[j]);
            acc[j] = fmaf(a4.y, w4.y, acc[j]);
            acc[j] = fmaf(a4.z, w4.z, acc[j]);
            acc[j] = fmaf(a4.w, w4.w, acc[j]);
          }
        }
        __syncthreads();
      }
      *(float4*)(Cdst + (size_t)m * 1536 + n0 + nq * 4) =
          make_float4(acc[0], acc[1], acc[2], acc[3]);
    }
    grid_barrier(cnt, gen);

    // ---------------- Phase B: gates + attention ----------------
    if (blk < NB) {
      const int b = blk;
      const float* ge = gi_emb + (size_t)(t * NB + b) * 1536;
      for (int j = tid; j < NH; j += 256) {
        float ir  = giA[b * 1536 + j]        + ge[j];
        float iz  = giA[b * 1536 + 512 + j]  + ge[512 + j];
        float inn = giA[b * 1536 + 1024 + j] + ge[1024 + j];
        float hr  = ghA[b * 1536 + j]        + b_hh[j];
        float hz  = ghA[b * 1536 + 512 + j]  + b_hh[512 + j];
        float hn  = ghA[b * 1536 + 1024 + j] + b_hh[1024 + j];
        float r  = 1.f / (1.f + expf(-(ir + hr)));
        float zg = 1.f / (1.f + expf(-(iz + hz)));
        float n  = tanhf(inn + r * hn);
        float h  = (1.f - zg) * n + zg * h_prev[b * NH + j];
        hL[j] = h;
        h_next[b * NH + j] = h;
      }
      __syncthreads();
      // scores: 4 lanes per s, float4 (64B contiguous per lane-quad)
      {
        int s = tid >> 2, sub = tid & 3;
        const float* ep = enc_proj + ((size_t)s * NB + b) * NH;
        float acc = 0.f;
        for (int g4 = sub * 4; g4 < NH; g4 += 16) {
          float4 e4 = *(const float4*)(ep + g4);
          float4 h4 = *(const float4*)&hL[g4];
          acc += e4.x * h4.x + e4.y * h4.y + e4.z * h4.z + e4.w * h4.w;
        }
        acc += __shfl_xor(acc, 1);
        acc += __shfl_xor(acc, 2);
        if (sub == 0) scs[s] = acc;
      }
      __syncthreads();
      if (tid < 64) {
        int len = len_src[b];
        float v = (tid < len) ? scs[tid] : -1e9f;
        float mm = v;
        for (int off = 32; off >= 1; off >>= 1) mm = fmaxf(mm, __shfl_xor(mm, off));
        float e = expf(v - mm);
        float ssum = e;
        for (int off = 32; off >= 1; off >>= 1) ssum += __shfl_xor(ssum, off);
        aw[tid] = e / ssum;
      }
      __syncthreads();
      for (int gg = tid; gg < NH; gg += 256) {
        float c = 0.f;
#pragma unroll 4
        for (int s2 = 0; s2 < NS; ++s2)
          c += aw[s2] * enc_out[((size_t)s2 * NB + b) * NH + gg];
        ctx_g[b * NH + gg] = c;
      }
    }
    grid_barrier(cnt, gen);

    // ---------------- Phase C: concat GEMM (n-sliced) ----------------
    if (blk < 64) {
      const int n0 = blk * 8;
      float* adst = attn_all + (size_t)(t + 1) * NB * NH;
      float acc0 = 0.f, acc1 = 0.f;
      for (int k0 = 0; k0 < 2 * NH; k0 += 64) {
        const float* Xsrc = (k0 < NH) ? (h_next + k0) : (ctx_g + (k0 - NH));
#pragma unroll
        for (int u = 0; u < 4; ++u)
          *(float4*)&As[am][ac4 + 4 * u] =
              *(const float4*)(Xsrc + (size_t)am * NH + ac4 + 4 * u);
        if (wn < 8)
          *(float4*)&Ws[wn][wc] =
              *(const float4*)(W_concat + (size_t)(n0 + wn) * (2 * NH) + k0 + wc);
        __syncthreads();
#pragma unroll
        for (int kc4 = 0; kc4 < 16; ++kc4) {
          float4 x4 = *(const float4*)&As[m][kc4 * 4];
          float4 w0 = *(const float4*)&Ws[nq * 2][kc4 * 4];
          float4 w1 = *(const float4*)&Ws[nq * 2 + 1][kc4 * 4];
          acc0 = fmaf(x4.x, w0.x, acc0); acc0 = fmaf(x4.y, w0.y, acc0);
          acc0 = fmaf(x4.z, w0.z, acc0); acc0 = fmaf(x4.w, w0.w, acc0);
          acc1 = fmaf(x4.x, w1.x, acc1); acc1 = fmaf(x4.y, w1.y, acc1);
          acc1 = fmaf(x4.z, w1.z, acc1); acc1 = fmaf(x4.w, w1.w, acc1);
        }
        __syncthreads();
      }
      int n = n0 + nq * 2;
      float v0 = tanhf(acc0 + b_concat[n]);
      float v1 = tanhf(acc1 + b_concat[n + 1]);
      *(float2*)(adst + (size_t)m * NH + n) = make_float2(v0, v1);
    }
    grid_barrier(cnt, gen);
  }
}

// ---------------------------------------------------------------------------
// Online single-pass log-softmax + argmax per row (1216 rows).
// ---------------------------------------------------------------------------
__global__ __launch_bounds__(256) void row_softmax_kernel(
    float* __restrict__ out, float* __restrict__ words)
{
  const int row = blockIdx.x;
  const int tid = threadIdx.x;
  float* p = out + (size_t)row * NV;
  __shared__ float sm[256];
  __shared__ int   si[256];
  __shared__ float ss[256];

  float mv = -INFINITY; int mi = 0; float s = 0.f;
  for (int i = tid; i < NV; i += 256) {
    float v = p[i];
    if (v > mv) {
      s = s * expf(mv - v) + 1.f;
      mv = v; mi = i;
    } else {
      s += expf(v - mv);
    }
  }
  sm[tid] = mv; si[tid] = mi; ss[tid] = s;
  __syncthreads();
  for (int off = 128; off >= 1; off >>= 1) {
    if (tid < off) {
      float m1 = sm[tid], m2 = sm[tid + off];
      float s1 = ss[tid], s2 = ss[tid + off];
      int   i1 = si[tid], i2 = si[tid + off];
      float M = fmaxf(m1, m2);
      ss[tid] = s1 * expf(m1 - M) + s2 * expf(m2 - M);
      if (m2 > m1 || (m2 == m1 && i2 < i1)) { sm[tid] = m2; si[tid] = i2; }
    }
    __syncthreads();
  }
  const float lse = sm[0] + logf(ss[0]);
  for (int i = tid; i < NV; i += 256) p[i] -= lse;
  if (tid == 0) words[row] = (float)si[0];
}

// init: zero attn slot 0, copy h0, zero barrier state (ws is poisoned 0xAA
// before every timed launch, so this must run every launch).
__global__ __launch_bounds__(256) void init_kernel(
    float* __restrict__ attn0, float* __restrict__ h0,
    const float* __restrict__ enc_final, unsigned* __restrict__ bar)
{
  int i = blockIdx.x * 256 + threadIdx.x;
  if (i < NB * NH) {
    attn0[i] = 0.f;
    h0[i] = enc_final[i];
  }
  if (i < 64) bar[i] = 0u;
}

extern "C" void kernel_launch(void* const* d_in, const int* in_sizes, int n_in,
                              void* d_out, int out_size, void* d_ws, size_t ws_size,
                              hipStream_t stream) {
  const int*   tgt       = (const int*)d_in[0];
  const int*   len_src   = (const int*)d_in[1];
  const float* enc_final = (const float*)d_in[3];
  const float* enc_out   = (const float*)d_in[4];
  const float* emb       = (const float*)d_in[6];
  const float* W_ih      = (const float*)d_in[7];
  const float* W_hh      = (const float*)d_in[8];
  const float* b_ih      = (const float*)d_in[9];
  const float* b_hh      = (const float*)d_in[10];
  const float* W_attn    = (const float*)d_in[11];
  const float* W_concat  = (const float*)d_in[12];
  const float* b_concat  = (const float*)d_in[13];
  const float* W_out     = (const float*)d_in[14];
  const float* b_out     = (const float*)d_in[15];
  float* out = (float*)d_out;

  // workspace layout (floats): total ~4.92M floats = 19.7 MB
  float* ws = (float*)d_ws;
  float* enc_proj = ws;                         // 64*64*512   = 2,097,152
  float* gi_emb   = enc_proj + 2097152;         // 1216*1536   = 1,867,776
  float* giA      = gi_emb + 1867776;           // 64*1536
  float* ghA      = giA + 98304;                // 64*1536
  float* hbuf     = ghA + 98304;                // 2*64*512
  float* attn_all = hbuf + 65536;               // 20*64*512
  float* ctx_g    = attn_all + 655360;          // 64*512
  unsigned* bar   = (unsigned*)(ctx_g + 32768); // 64 uints

  init_kernel<<<128, 256, 0, stream>>>(attn_all, hbuf, enc_final, bar);

  // enc_proj = enc_out @ W_attn^T   (M=4096, N=512, K=512)
  linear_kernel<<<dim3(4, 64), 256, 0, stream>>>(
      enc_out, 512, W_attn, 512, nullptr, enc_proj, 512, 512, 0);

  // gi_emb = emb[tgt] @ W_ih[:, :256]^T + b_ih  (M=1216, N=1536, K=256)
  emb_linear_kernel<<<dim3(12, 19), 256, 0, stream>>>(
      emb, tgt, W_ih, b_ih, gi_emb);

  // whole recurrence: one cooperative kernel with fast custom barriers
  void* kargs[] = {
    (void*)&gi_emb, (void*)&giA, (void*)&ghA, (void*)&hbuf, (void*)&attn_all,
    (void*)&ctx_g, (void*)&enc_proj, (void*)&enc_out, (void*)&len_src,
    (void*)&W_ih, (void*)&W_hh, (void*)&b_hh, (void*)&W_concat,
    (void*)&b_concat, (void*)&bar
  };
  hipLaunchCooperativeKernel((const void*)recur_kernel, dim3(NBLK), dim3(256),
                             kargs, 0, stream);

  // logits for all steps: (1216 x 512) @ (512 x 32000), XCD-swizzled
  logits_kernel<<<4864, 256, 0, stream>>>(
      attn_all + NB * NH, W_out, b_out, out);

  // online log-softmax + argmax words
  row_softmax_kernel<<<TSTEPS * NB, 256, 0, stream>>>(
      out, out + (size_t)TSTEPS * NB * NV);
}